// Round 10
// baseline (150.360 us; speedup 1.0000x reference)
//
#include <hip/hip_runtime.h>

// SelfAttention (SAGAN-style), MI355X — bf16 MFMA implementation, v10.
// Math: out[b,c,n] = gamma * sum_m [exp(S[m,n]) / Z[m]] * V[b,c,m] + x[b,c,n]
//   S[m,n] = sum_q Q[q,m] K[q,n],  Z[m] = sum_j exp(S[m,j]).
// exp2 trick: Q pre-scaled by log2(e); L[m] = -log2(Z[m]) folded into the
// S-MFMA accumulator init => P = exp2(S' + L) with zero extra VALU.
//
// v10 (R9 post-mortem): attn is stall-bound — loads issued at point of use
// put 200-900cyc L2/HBM latency on the per-iter critical chain; occupancy
// 20->30% was neutral (R8). Fix: register-prefetch next-iter Q/L/V one full
// iteration ahead (wrap-indexed), same proven 256-thread/4-wave body.
// (512-thread attn failed twice with ~unnormalized-scale errors; banned.)

constexpr int Bn = 4, Cc = 64, Q8 = 8, Np = 4096;
constexpr int QK_STR = 32;  // padded q dim (shorts) per position
constexpr int PSTR = 40;    // attn Plds row stride in shorts (80B, 16B-aligned)
constexpr int NSL = 8;      // zsum n-slices

typedef float f32x4 __attribute__((ext_vector_type(4)));
typedef short short8 __attribute__((ext_vector_type(8)));

__device__ inline unsigned int f2bf(float x) {  // RNE f32->bf16 (as u16)
    unsigned int u = __float_as_uint(x);
    u += 0x7fff + ((u >> 16) & 1);
    return u >> 16;
}
__device__ inline float bf2f(unsigned int u) { return __uint_as_float(u << 16); }

__device__ inline unsigned cvt_pk_bf16(float a, float b) {  // lo=bf16(a), hi=bf16(b)
    unsigned r;
    asm("v_cvt_pk_bf16_f32 %0, %1, %2" : "=v"(r) : "v"(a), "v"(b));
    return r;
}
__device__ inline float exp2g(float x) {
#if __has_builtin(__builtin_amdgcn_exp2f)
    return __builtin_amdgcn_exp2f(x);
#else
    return exp2f(x);
#endif
}
__device__ inline float log2g(float x) {
#if __has_builtin(__builtin_amdgcn_logf)
    return __builtin_amdgcn_logf(x);
#else
    return log2f(x);
#endif
}

// ---------------- kernel 1: QKV projections, lane-per-position, 8 slices ----------------
__global__ __launch_bounds__(64) void qkv_v3(
    const float* __restrict__ x,
    const float* __restrict__ Wq, const float* __restrict__ bq,
    const float* __restrict__ Wk, const float* __restrict__ bk,
    const float* __restrict__ Wv, const float* __restrict__ bv,
    unsigned short* __restrict__ Qp, unsigned short* __restrict__ Kp,
    unsigned short* __restrict__ Vb)
{
    const int lane = threadIdx.x;
    const int gpos = blockIdx.x * 64;        // over Bn*Np
    const int os = blockIdx.y;               // uniform -> scalar W loads
    const int b = gpos >> 12, n = (gpos & (Np - 1)) + lane;
    const float LOG2E = 1.4426950408889634f;

    float xv[Cc];
    const float* xp = x + (size_t)(b * Cc) * Np + n;
    #pragma unroll
    for (int c = 0; c < Cc; c++) xv[c] = xp[(size_t)c * Np];

    if (os <= 1) {
        const float* W = (os == 0) ? Wq : Wk;
        const float* bb = (os == 0) ? bq : bk;
        const float sc = (os == 0) ? LOG2E : 1.0f;
        unsigned pk[4];
        #pragma unroll
        for (int p = 0; p < 4; p++) {
            float a0 = bb[2 * p], a1 = bb[2 * p + 1];
            #pragma unroll
            for (int c = 0; c < Cc; c++) {
                a0 += W[(2 * p) * Cc + c] * xv[c];
                a1 += W[(2 * p + 1) * Cc + c] * xv[c];
            }
            pk[p] = f2bf(a0 * sc) | (f2bf(a1 * sc) << 16);
        }
        unsigned short* row = (os == 0 ? Qp : Kp) + (size_t)(b * Np + n) * QK_STR;
        *(uint4*)row = make_uint4(pk[0], pk[1], pk[2], pk[3]);
        *(uint4*)(row + 8)  = make_uint4(0, 0, 0, 0);
        *(uint4*)(row + 16) = make_uint4(0, 0, 0, 0);
        *(uint4*)(row + 24) = make_uint4(0, 0, 0, 0);
        const int vbase = 60 + (os == 0 ? 2 : 0);  // os0: 62,63; os1: 60,61
        #pragma unroll
        for (int o = 0; o < 2; o++) {
            const int vr = vbase + o;
            float a = bv[vr];
            #pragma unroll
            for (int c = 0; c < Cc; c++) a += Wv[vr * Cc + c] * xv[c];
            Vb[(size_t)(b * Cc + vr) * Np + n] = (unsigned short)f2bf(a);
        }
    } else {
        const int vbase = (os - 2) * 10;     // 0,10,...,50
        #pragma unroll
        for (int o = 0; o < 10; o++) {
            const int vr = vbase + o;
            float a = bv[vr];
            #pragma unroll
            for (int c = 0; c < Cc; c++) a += Wv[vr * Cc + c] * xv[c];
            Vb[(size_t)(b * Cc + vr) * Np + n] = (unsigned short)f2bf(a);
        }
    }
}

// ---------------- kernel 2: Z partials via MFMA, direct-from-L2, prefetched ----------------
// grid (Np/64, NSL, Bn), block 256 (4 waves). No LDS, no barriers.
__global__ __launch_bounds__(256) void zsum_v4(
    const unsigned short* __restrict__ Qp, const unsigned short* __restrict__ Kp,
    float* __restrict__ ZP)
{
    const int tid = threadIdx.x, w = tid >> 6, lane = tid & 63;
    const int quad = lane >> 4, l15 = lane & 15;
    const int bz = blockIdx.z, ns = blockIdx.y;
    const int m0 = blockIdx.x * 64 + w * 16;
    const int NS = Np / NSL;  // 512, power of 2

    short8 qa = *(const short8*)&Qp[((size_t)(bz * Np + m0 + l15)) * QK_STR + quad * 8];
    const unsigned short* kbase = Kp + (size_t)bz * Np * QK_STR;
    const int nbase = ns * NS;

    short8 kb = *(const short8*)&kbase[(size_t)(nbase + l15) * QK_STR + quad * 8];
    float z0 = 0.f, z1 = 0.f, z2 = 0.f, z3 = 0.f;
    for (int nt = 0; nt < NS; nt += 16) {
        short8 kcur = kb;
        int ntn = (nt + 16) & (NS - 1);       // wrap; extra load harmless
        kb = *(const short8*)&kbase[(size_t)(nbase + ntn + l15) * QK_STR + quad * 8];
        f32x4 s = __builtin_amdgcn_mfma_f32_16x16x32_bf16(
            qa, kcur, f32x4{0.f, 0.f, 0.f, 0.f}, 0, 0, 0);
        z0 += exp2g(s[0]); z1 += exp2g(s[1]);
        z2 += exp2g(s[2]); z3 += exp2g(s[3]);
    }
    #pragma unroll
    for (int mask = 1; mask < 16; mask <<= 1) {
        z0 += __shfl_xor(z0, mask); z1 += __shfl_xor(z1, mask);
        z2 += __shfl_xor(z2, mask); z3 += __shfl_xor(z3, mask);
    }
    if (l15 == 0) {
        float4 v = make_float4(z0, z1, z2, z3);
        *(float4*)&ZP[((size_t)(bz * NSL + ns)) * Np + m0 + quad * 4] = v;
    }
}

// ---------------- kernel 3: L[m] = -log2(Z[m]) ----------------
__global__ __launch_bounds__(256) void zred(
    const float* __restrict__ ZP, float* __restrict__ Lg)
{
    int i = blockIdx.x * 256 + threadIdx.x;  // over Bn*Np
    int b = i >> 12, m = i & (Np - 1);
    float z = 0.f;
    #pragma unroll
    for (int s = 0; s < NSL; s++) z += ZP[((size_t)(b * NSL + s)) * Np + m];
    Lg[(size_t)b * Np + m] = -log2g(z);
}

// ---------------- kernel 4: out partials via MFMA, prefetch-pipelined ----------------
// PROVEN geometry: grid (Np/128, SL, Bn), block 256 (4 waves), wave w owns
// 32 n (two 16-n subtiles); Plds rows wave-private, no barriers.
// v10: Q/L/V for iteration i+1 are loaded into registers during iteration i.
__global__ __launch_bounds__(256) void attn_v6(
    const unsigned short* __restrict__ Qp, const unsigned short* __restrict__ Kp,
    const unsigned short* __restrict__ Vb, const float* __restrict__ Lg,
    unsigned short* __restrict__ PO, int Ms, int SL)
{
    __shared__ unsigned short Plds[128 * PSTR];  // [n_local][m_local]
    const int tid = threadIdx.x, w = tid >> 6, lane = tid & 63;
    const int quad = lane >> 4, l15 = lane & 15;
    const int bz = blockIdx.z, by = blockIdx.y, nb = blockIdx.x * 128;

    const unsigned short* qbase = Qp + (size_t)bz * Np * QK_STR;
    const float* lbase = Lg + (size_t)bz * Np;
    const unsigned short* vb = Vb + (size_t)bz * Cc * Np;

    short8 kf[2];
    #pragma unroll
    for (int t = 0; t < 2; t++) {
        int n = nb + (2 * w + t) * 16 + l15;
        kf[t] = *(const short8*)&Kp[((size_t)(bz * Np + n)) * QK_STR + quad * 8];
    }
    f32x4 acc[4][2];
    #pragma unroll
    for (int ct = 0; ct < 4; ct++)
        #pragma unroll
        for (int t = 0; t < 2; t++) acc[ct][t] = f32x4{0.f, 0.f, 0.f, 0.f};

    const int m_base = by * Ms;

    // prologue: loads for iteration 0
    short8 qa[2];
    f32x4 Lc[2];
    short8 ua[4];
    #pragma unroll
    for (int mt = 0; mt < 2; mt++) {
        qa[mt] = *(const short8*)
            &qbase[(size_t)(m_base + mt * 16 + l15) * QK_STR + quad * 8];
        Lc[mt] = *(const f32x4*)&lbase[m_base + mt * 16 + quad * 4];
    }
    #pragma unroll
    for (int ct = 0; ct < 4; ct++)
        ua[ct] = *(const short8*)&vb[(size_t)(ct * 16 + l15) * Np + m_base + quad * 8];

    for (int mi = 0; mi < Ms; mi += 32) {
        const int m0 = m_base + mi;
        // phase 1: S-MFMAs with current qa/Lc
        f32x4 s[2][2];
        #pragma unroll
        for (int mt = 0; mt < 2; mt++)
            #pragma unroll
            for (int t = 0; t < 2; t++)
                s[mt][t] = __builtin_amdgcn_mfma_f32_16x16x32_bf16(
                    qa[mt], kf[t], Lc[mt], 0, 0, 0);

        // prefetch iteration i+1 (wrap-indexed; harmless extra loads on last iter)
        const int mn = m_base + ((mi + 32) & (Ms - 1));
        short8 qaN[2];
        f32x4 LcN[2];
        short8 uaN[4];
        #pragma unroll
        for (int mt = 0; mt < 2; mt++) {
            qaN[mt] = *(const short8*)
                &qbase[(size_t)(mn + mt * 16 + l15) * QK_STR + quad * 8];
            LcN[mt] = *(const f32x4*)&lbase[mn + mt * 16 + quad * 4];
        }
        #pragma unroll
        for (int ct = 0; ct < 4; ct++)
            uaN[ct] = *(const short8*)&vb[(size_t)(ct * 16 + l15) * Np + mn + quad * 8];

        // exp2 + pack + LDS write
        #pragma unroll
        for (int mt = 0; mt < 2; mt++)
            #pragma unroll
            for (int t = 0; t < 2; t++) {
                unsigned p01 = cvt_pk_bf16(exp2g(s[mt][t][0]), exp2g(s[mt][t][1]));
                unsigned p23 = cvt_pk_bf16(exp2g(s[mt][t][2]), exp2g(s[mt][t][3]));
                int nl = (2 * w + t) * 16 + l15;
                *(uint2*)&Plds[nl * PSTR + mt * 16 + quad * 4] = make_uint2(p01, p23);
            }
        // LDS read (wave-private rows) + V-MFMAs with current ua
        short8 pb[2];
        #pragma unroll
        for (int t = 0; t < 2; t++)
            pb[t] = *(const short8*)&Plds[(w * 32 + t * 16 + l15) * PSTR + quad * 8];
        #pragma unroll
        for (int ct = 0; ct < 4; ct++)
            #pragma unroll
            for (int t = 0; t < 2; t++)
                acc[ct][t] = __builtin_amdgcn_mfma_f32_16x16x32_bf16(
                    ua[ct], pb[t], acc[ct][t], 0, 0, 0);

        // rotate prefetched registers
        #pragma unroll
        for (int mt = 0; mt < 2; mt++) { qa[mt] = qaN[mt]; Lc[mt] = LcN[mt]; }
        #pragma unroll
        for (int ct = 0; ct < 4; ct++) ua[ct] = uaN[ct];
    }
    unsigned short* po = PO + ((size_t)((bz * SL + by) * Cc)) * Np + nb;
    #pragma unroll
    for (int ct = 0; ct < 4; ct++)
        #pragma unroll
        for (int t = 0; t < 2; t++) {
            int c = ct * 16 + quad * 4, n = w * 32 + t * 16 + l15;
            #pragma unroll
            for (int r = 0; r < 4; r++)
                po[(size_t)(c + r) * Np + n] = (unsigned short)f2bf(acc[ct][t][r]);
        }
}

// ---------------- kernel 5: combine slices + gamma*out + x (8-wide) ----------------
__global__ __launch_bounds__(256) void combine_kernel(
    const unsigned short* __restrict__ PO, const float* __restrict__ x,
    const float* __restrict__ gamma, float* __restrict__ out, int sl2)
{
    int idx8 = (blockIdx.x * 256 + threadIdx.x) * 8;  // over Bn*Cc*Np
    int b = idx8 >> 18;
    int c = (idx8 >> 12) & 63;
    int n = idx8 & (Np - 1);
    float o[8];
    #pragma unroll
    for (int i = 0; i < 8; i++) o[i] = 0.f;
    for (int sl = 0; sl < sl2; ++sl) {
        uint4 u = *(const uint4*)&PO[(size_t)((b * sl2 + sl) * Cc + c) * Np + n];
        o[0] += bf2f(u.x & 0xffff); o[1] += bf2f(u.x >> 16);
        o[2] += bf2f(u.y & 0xffff); o[3] += bf2f(u.y >> 16);
        o[4] += bf2f(u.z & 0xffff); o[5] += bf2f(u.z >> 16);
        o[6] += bf2f(u.w & 0xffff); o[7] += bf2f(u.w >> 16);
    }
    float g = gamma[0];
    float4 x0 = *(const float4*)&x[idx8];
    float4 x1 = *(const float4*)&x[idx8 + 4];
    float4 r0 = make_float4(g * o[0] + x0.x, g * o[1] + x0.y,
                            g * o[2] + x0.z, g * o[3] + x0.w);
    float4 r1 = make_float4(g * o[4] + x1.x, g * o[5] + x1.y,
                            g * o[6] + x1.z, g * o[7] + x1.w);
    *(float4*)&out[idx8] = r0;
    *(float4*)&out[idx8 + 4] = r1;
}

extern "C" void kernel_launch(void* const* d_in, const int* in_sizes, int n_in,
                              void* d_out, int out_size, void* d_ws, size_t ws_size,
                              hipStream_t stream)
{
    const float* x     = (const float*)d_in[0];
    const float* Wq    = (const float*)d_in[1];
    const float* bq    = (const float*)d_in[2];
    const float* Wk    = (const float*)d_in[3];
    const float* bk    = (const float*)d_in[4];
    const float* Wv    = (const float*)d_in[5];
    const float* bv    = (const float*)d_in[6];
    const float* gamma = (const float*)d_in[7];
    float* out = (float*)d_out;

    unsigned short* Qp = (unsigned short*)d_ws;               // 1 MB
    unsigned short* Kp = Qp + (size_t)Bn * Np * QK_STR;       // 1 MB
    unsigned short* Vb = Kp + (size_t)Bn * Np * QK_STR;       // 2 MB (bf16 V, unnormalized)
    float* Lg   = (float*)(Vb + (size_t)Bn * Cc * Np);        // 64 KB: -log2(Z)
    float* ZP   = Lg + (size_t)Bn * Np;                       // NSL partials, 512 KB
    unsigned short* PO = (unsigned short*)(ZP + (size_t)Bn * NSL * Np);  // SL * 2 MB

    size_t baseB = (size_t)Bn * Np * QK_STR * 2 * 2 + (size_t)Bn * Cc * Np * 2
                 + (size_t)Bn * Np * 4 + (size_t)Bn * NSL * Np * 4;
    int SL = 8;  // m-slices for attn partials (1024 blocks)
    while (SL > 1 && baseB + (size_t)Bn * SL * Cc * Np * 2 > ws_size) SL >>= 1;

    qkv_v3<<<dim3(Bn * Np / 64, 8), 64, 0, stream>>>(x, Wq, bq, Wk, bk, Wv, bv,
                                                     Qp, Kp, Vb);
    zsum_v4<<<dim3(Np / 64, NSL, Bn), 256, 0, stream>>>(Qp, Kp, ZP);
    zred<<<Bn * Np / 256, 256, 0, stream>>>(ZP, Lg);
    attn_v6<<<dim3(Np / 128, SL, Bn), 256, 0, stream>>>(Qp, Kp, Vb, Lg,
                                                        PO, Np / SL, SL);
    combine_kernel<<<Bn * Cc * Np / (256 * 8), 256, 0, stream>>>(PO, x, gamma, out, SL);
}

// Round 12
// 141.360 us; speedup vs baseline: 1.0637x; 1.0637x over previous
//
#include <hip/hip_runtime.h>

// SelfAttention (SAGAN-style), MI355X — bf16 MFMA implementation, v12.
// Math: out[b,c,n] = gamma * sum_m [exp(S[m,n]) / Z[m]] * V[b,c,m] + x[b,c,n]
//   S[m,n] = sum_q Q[q,m] K[q,n],  Z[m] = sum_j exp(S[m,j]).
// exp2 trick: Q pre-scaled by log2(e); L[m] = -log2(Z[m]) folded into the
// S-MFMA accumulator init => P = exp2(S' + L) with zero extra VALU.
//
// v12 (R11 post-mortem): v11 changed three things at once and failed
// unattributably. v12 = v9 (last pass, 147 µs) with ONE change: qkv is the
// MFMA GEMM version but emitting the PROVEN padded [n][32] Q/K layout
// (explicit zero-pad stores). zsum/attn/zred/combine are byte-identical
// to v9. Failure clusters so far (do not reintroduce):
//   - 512-thread attn blocks (v6/v7)
//   - dense [n][8] Q/K + quad-predicated frag loads (v11, unattributed)

constexpr int Bn = 4, Cc = 64, Q8 = 8, Np = 4096;
constexpr int QK_STR = 32;  // padded q dim (shorts) per position
constexpr int PSTR = 40;    // attn Plds row stride in shorts (80B, 16B-aligned)
constexpr int NSL = 8;      // zsum n-slices
constexpr int XSTR = 72;    // qkv xT row stride in shorts (144B, 16B-aligned)

typedef float f32x4 __attribute__((ext_vector_type(4)));
typedef short short8 __attribute__((ext_vector_type(8)));

__device__ inline unsigned int f2bf(float x) {  // RNE f32->bf16 (as u16)
    unsigned int u = __float_as_uint(x);
    u += 0x7fff + ((u >> 16) & 1);
    return u >> 16;
}
__device__ inline float bf2f(unsigned int u) { return __uint_as_float(u << 16); }

__device__ inline unsigned cvt_pk_bf16(float a, float b) {  // lo=bf16(a), hi=bf16(b)
    unsigned r;
    asm("v_cvt_pk_bf16_f32 %0, %1, %2" : "=v"(r) : "v"(a), "v"(b));
    return r;
}
__device__ inline float exp2g(float x) {
#if __has_builtin(__builtin_amdgcn_exp2f)
    return __builtin_amdgcn_exp2f(x);
#else
    return exp2f(x);
#endif
}
__device__ inline float log2g(float x) {
#if __has_builtin(__builtin_amdgcn_logf)
    return __builtin_amdgcn_logf(x);
#else
    return log2f(x);
#endif
}

// ---------------- kernel 1: QKV projections via MFMA (padded Q/K output) ----------------
// Out[o, n] = sum_c W[o,c] x[c,n] + b[o].  o-tiles: ot 0 = {Q rows 0-7, K rows
// 0-7} (A rows 0-7 = Q, 8-15 = K); ot 1..4 = V rows (ot-1)*16 .. +15.
// Grid (Bn*Np/64, 5), block 64 (1 wave). x tile staged transposed bf16 in LDS.
__global__ __launch_bounds__(64) void qkv_mfma(
    const float* __restrict__ x,
    const float* __restrict__ Wq, const float* __restrict__ bq,
    const float* __restrict__ Wk, const float* __restrict__ bk,
    const float* __restrict__ Wv, const float* __restrict__ bv,
    unsigned short* __restrict__ Qp, unsigned short* __restrict__ Kp,
    unsigned short* __restrict__ Vb)
{
    __shared__ unsigned short xT[64 * XSTR];  // [n_local][c] bf16
    const int lane = threadIdx.x;
    const int quad = lane >> 4, l15 = lane & 15;
    const int gpos = blockIdx.x * 64;        // over Bn*Np
    const int ot = blockIdx.y;               // 0..4
    const int b = gpos >> 12, n0 = gpos & (Np - 1);
    const float LOG2E = 1.4426950408889634f;

    // stage x tile transposed: lane owns channel c = lane
    {
        const float* xrow = x + (size_t)(b * Cc + lane) * Np + n0;
        #pragma unroll
        for (int i4 = 0; i4 < 16; i4++) {
            float4 v = *(const float4*)&xrow[i4 * 4];
            int nb4 = i4 * 4;
            xT[(nb4 + 0) * XSTR + lane] = (unsigned short)f2bf(v.x);
            xT[(nb4 + 1) * XSTR + lane] = (unsigned short)f2bf(v.y);
            xT[(nb4 + 2) * XSTR + lane] = (unsigned short)f2bf(v.z);
            xT[(nb4 + 3) * XSTR + lane] = (unsigned short)f2bf(v.w);
        }
    }
    __syncthreads();

    // A-frags from W: A[i = o_local = l15][k = c = kf*32 + quad*8 + jj]
    const float* Wrow;
    if (ot == 0) Wrow = (l15 < 8) ? (Wq + l15 * Cc) : (Wk + (l15 - 8) * Cc);
    else         Wrow = Wv + ((ot - 1) * 16 + l15) * Cc;
    short8 wa[2];
    #pragma unroll
    for (int kf = 0; kf < 2; kf++) {
        #pragma unroll
        for (int jj = 0; jj < 8; jj++)
            wa[kf][jj] = (short)f2bf(Wrow[kf * 32 + quad * 8 + jj]);
    }
    // bias per C/D row o = quad*4 + r
    float bias[4];
    if (ot == 0) {
        const float* bb = (quad < 2) ? bq : bk;
        int off = (quad & 1) * 4;
        #pragma unroll
        for (int r = 0; r < 4; r++) bias[r] = bb[off + r];
    } else {
        #pragma unroll
        for (int r = 0; r < 4; r++) bias[r] = bv[(ot - 1) * 16 + quad * 4 + r];
    }

    #pragma unroll
    for (int nt = 0; nt < 4; nt++) {
        // B-frags: B[k = c = quad*8+jj (+32)][j = n_local = l15]
        short8 xb0 = *(const short8*)&xT[(nt * 16 + l15) * XSTR + quad * 8];
        short8 xb1 = *(const short8*)&xT[(nt * 16 + l15) * XSTR + 32 + quad * 8];
        f32x4 cc = __builtin_amdgcn_mfma_f32_16x16x32_bf16(
            wa[0], xb0, f32x4{0.f, 0.f, 0.f, 0.f}, 0, 0, 0);
        cc = __builtin_amdgcn_mfma_f32_16x16x32_bf16(wa[1], xb1, cc, 0, 0, 0);
        int n = n0 + nt * 16 + l15;
        if (ot == 0) {
            float v0 = cc[0] + bias[0], v1 = cc[1] + bias[1];
            float v2 = cc[2] + bias[2], v3 = cc[3] + bias[3];
            if (quad < 2) { v0 *= LOG2E; v1 *= LOG2E; v2 *= LOG2E; v3 *= LOG2E; }
            unsigned p01 = cvt_pk_bf16(v0, v1), p23 = cvt_pk_bf16(v2, v3);
            // padded [n][32] row: data at q-offset (quad&1)*4, zeros at [8,32)
            unsigned short* rowp = (quad < 2 ? Qp : Kp)
                + ((size_t)(b * Np + n)) * QK_STR;
            *(uint2*)(rowp + (quad & 1) * 4) = make_uint2(p01, p23);
            if ((quad & 1) == 0) {
                *(uint4*)(rowp + 8) = make_uint4(0, 0, 0, 0);
            } else {
                *(uint4*)(rowp + 16) = make_uint4(0, 0, 0, 0);
                *(uint4*)(rowp + 24) = make_uint4(0, 0, 0, 0);
            }
        } else {
            #pragma unroll
            for (int r = 0; r < 4; r++) {
                int vr = (ot - 1) * 16 + quad * 4 + r;
                Vb[(size_t)(b * Cc + vr) * Np + n] =
                    (unsigned short)f2bf(cc[r] + bias[r]);
            }
        }
    }
}

// ---------------- kernel 2: Z partials via MFMA, direct-from-L2 (v9 verbatim) ----------------
__global__ __launch_bounds__(256) void zsum_v3(
    const unsigned short* __restrict__ Qp, const unsigned short* __restrict__ Kp,
    float* __restrict__ ZP)
{
    const int tid = threadIdx.x, w = tid >> 6, lane = tid & 63;
    const int quad = lane >> 4, l15 = lane & 15;
    const int bz = blockIdx.z, ns = blockIdx.y;
    const int m0 = blockIdx.x * 64 + w * 16;

    short8 qa = *(const short8*)&Qp[((size_t)(bz * Np + m0 + l15)) * QK_STR + quad * 8];
    const unsigned short* kbase = Kp + (size_t)bz * Np * QK_STR;
    const int nbase = ns * (Np / NSL);

    float z0 = 0.f, z1 = 0.f, z2 = 0.f, z3 = 0.f;
    #pragma unroll 4
    for (int nt = 0; nt < Np / NSL; nt += 16) {
        short8 kb = *(const short8*)
            &kbase[(size_t)(nbase + nt + l15) * QK_STR + quad * 8];
        f32x4 s = __builtin_amdgcn_mfma_f32_16x16x32_bf16(
            qa, kb, f32x4{0.f, 0.f, 0.f, 0.f}, 0, 0, 0);
        z0 += exp2g(s[0]); z1 += exp2g(s[1]);
        z2 += exp2g(s[2]); z3 += exp2g(s[3]);
    }
    #pragma unroll
    for (int mask = 1; mask < 16; mask <<= 1) {
        z0 += __shfl_xor(z0, mask); z1 += __shfl_xor(z1, mask);
        z2 += __shfl_xor(z2, mask); z3 += __shfl_xor(z3, mask);
    }
    if (l15 == 0) {
        float4 v = make_float4(z0, z1, z2, z3);
        *(float4*)&ZP[((size_t)(bz * NSL + ns)) * Np + m0 + quad * 4] = v;
    }
}

// ---------------- kernel 3: L[m] = -log2(Z[m]) ----------------
__global__ __launch_bounds__(256) void zred(
    const float* __restrict__ ZP, float* __restrict__ Lg)
{
    int i = blockIdx.x * 256 + threadIdx.x;  // over Bn*Np
    int b = i >> 12, m = i & (Np - 1);
    float z = 0.f;
    #pragma unroll
    for (int s = 0; s < NSL; s++) z += ZP[((size_t)(b * NSL + s)) * Np + m];
    Lg[(size_t)b * Np + m] = -log2g(z);
}

// ---------------- kernel 4: out partials via MFMA, barrier-free (v9 verbatim) ----------------
// PROVEN geometry: grid (Np/128, SL, Bn), block 256 (4 waves), wave w owns
// 32 n (two 16-n subtiles); Plds rows wave-private.
__global__ __launch_bounds__(256) void attn_v4(
    const unsigned short* __restrict__ Qp, const unsigned short* __restrict__ Kp,
    const unsigned short* __restrict__ Vb, const float* __restrict__ Lg,
    unsigned short* __restrict__ PO, int Ms, int SL)
{
    __shared__ unsigned short Plds[128 * PSTR];  // [n_local][m_local]
    const int tid = threadIdx.x, w = tid >> 6, lane = tid & 63;
    const int quad = lane >> 4, l15 = lane & 15;
    const int bz = blockIdx.z, by = blockIdx.y, nb = blockIdx.x * 128;

    short8 kf[2];
    #pragma unroll
    for (int t = 0; t < 2; t++) {
        int n = nb + (2 * w + t) * 16 + l15;
        kf[t] = *(const short8*)&Kp[((size_t)(bz * Np + n)) * QK_STR + quad * 8];
    }
    f32x4 acc[4][2];
    #pragma unroll
    for (int ct = 0; ct < 4; ct++)
        #pragma unroll
        for (int t = 0; t < 2; t++) acc[ct][t] = f32x4{0.f, 0.f, 0.f, 0.f};

    const int m_base = by * Ms;
    for (int mi = 0; mi < Ms; mi += 32) {
        const int m0 = m_base + mi;
        // phase 1: P[m0..m0+31][wave's 32 n] = exp2(S' + L[m]), bf16, into LDS
        #pragma unroll
        for (int mt = 0; mt < 2; mt++) {
            short8 qa = *(const short8*)
                &Qp[((size_t)(bz * Np + m0 + mt * 16 + l15)) * QK_STR + quad * 8];
            f32x4 Lc = *(const f32x4*)
                &Lg[(size_t)bz * Np + m0 + mt * 16 + quad * 4];
            #pragma unroll
            for (int t = 0; t < 2; t++) {
                f32x4 s = __builtin_amdgcn_mfma_f32_16x16x32_bf16(qa, kf[t], Lc, 0, 0, 0);
                unsigned p01 = cvt_pk_bf16(exp2g(s[0]), exp2g(s[1]));
                unsigned p23 = cvt_pk_bf16(exp2g(s[2]), exp2g(s[3]));
                int nl = (2 * w + t) * 16 + l15;
                *(uint2*)&Plds[nl * PSTR + mt * 16 + quad * 4] = make_uint2(p01, p23);
            }
        }
        // phase 2: acc[c, n] += V[c, m0..31] * P[m0..31, n]  (wave-private rows)
        short8 pb[2];
        #pragma unroll
        for (int t = 0; t < 2; t++)
            pb[t] = *(const short8*)&Plds[(w * 32 + t * 16 + l15) * PSTR + quad * 8];
        #pragma unroll
        for (int ct = 0; ct < 4; ct++) {
            short8 ua = *(const short8*)
                &Vb[((size_t)(bz * Cc + ct * 16 + l15)) * Np + m0 + quad * 8];
            #pragma unroll
            for (int t = 0; t < 2; t++)
                acc[ct][t] = __builtin_amdgcn_mfma_f32_16x16x32_bf16(
                    ua, pb[t], acc[ct][t], 0, 0, 0);
        }
    }
    unsigned short* po = PO + ((size_t)((bz * SL + by) * Cc)) * Np + nb;
    #pragma unroll
    for (int ct = 0; ct < 4; ct++)
        #pragma unroll
        for (int t = 0; t < 2; t++) {
            int c = ct * 16 + quad * 4, n = w * 32 + t * 16 + l15;
            #pragma unroll
            for (int r = 0; r < 4; r++)
                po[(size_t)(c + r) * Np + n] = (unsigned short)f2bf(acc[ct][t][r]);
        }
}

// ---------------- kernel 5: combine slices + gamma*out + x (8-wide) ----------------
__global__ __launch_bounds__(256) void combine_kernel(
    const unsigned short* __restrict__ PO, const float* __restrict__ x,
    const float* __restrict__ gamma, float* __restrict__ out, int sl2)
{
    int idx8 = (blockIdx.x * 256 + threadIdx.x) * 8;  // over Bn*Cc*Np
    int b = idx8 >> 18;
    int c = (idx8 >> 12) & 63;
    int n = idx8 & (Np - 1);
    float o[8];
    #pragma unroll
    for (int i = 0; i < 8; i++) o[i] = 0.f;
    for (int sl = 0; sl < sl2; ++sl) {
        uint4 u = *(const uint4*)&PO[(size_t)((b * sl2 + sl) * Cc + c) * Np + n];
        o[0] += bf2f(u.x & 0xffff); o[1] += bf2f(u.x >> 16);
        o[2] += bf2f(u.y & 0xffff); o[3] += bf2f(u.y >> 16);
        o[4] += bf2f(u.z & 0xffff); o[5] += bf2f(u.z >> 16);
        o[6] += bf2f(u.w & 0xffff); o[7] += bf2f(u.w >> 16);
    }
    float g = gamma[0];
    float4 x0 = *(const float4*)&x[idx8];
    float4 x1 = *(const float4*)&x[idx8 + 4];
    float4 r0 = make_float4(g * o[0] + x0.x, g * o[1] + x0.y,
                            g * o[2] + x0.z, g * o[3] + x0.w);
    float4 r1 = make_float4(g * o[4] + x1.x, g * o[5] + x1.y,
                            g * o[6] + x1.z, g * o[7] + x1.w);
    *(float4*)&out[idx8] = r0;
    *(float4*)&out[idx8 + 4] = r1;
}

extern "C" void kernel_launch(void* const* d_in, const int* in_sizes, int n_in,
                              void* d_out, int out_size, void* d_ws, size_t ws_size,
                              hipStream_t stream)
{
    const float* x     = (const float*)d_in[0];
    const float* Wq    = (const float*)d_in[1];
    const float* bq    = (const float*)d_in[2];
    const float* Wk    = (const float*)d_in[3];
    const float* bk    = (const float*)d_in[4];
    const float* Wv    = (const float*)d_in[5];
    const float* bv    = (const float*)d_in[6];
    const float* gamma = (const float*)d_in[7];
    float* out = (float*)d_out;

    unsigned short* Qp = (unsigned short*)d_ws;               // 1 MB (padded [n][32])
    unsigned short* Kp = Qp + (size_t)Bn * Np * QK_STR;       // 1 MB
    unsigned short* Vb = Kp + (size_t)Bn * Np * QK_STR;       // 2 MB (bf16 V)
    float* Lg   = (float*)(Vb + (size_t)Bn * Cc * Np);        // 64 KB: -log2(Z)
    float* ZP   = Lg + (size_t)Bn * Np;                       // NSL partials, 512 KB
    unsigned short* PO = (unsigned short*)(ZP + (size_t)Bn * NSL * Np);  // SL * 2 MB

    size_t baseB = (size_t)Bn * Np * QK_STR * 2 * 2 + (size_t)Bn * Cc * Np * 2
                 + (size_t)Bn * Np * 4 + (size_t)Bn * NSL * Np * 4;
    int SL = 8;  // m-slices for attn partials (1024 blocks)
    while (SL > 1 && baseB + (size_t)Bn * SL * Cc * Np * 2 > ws_size) SL >>= 1;

    qkv_mfma<<<dim3(Bn * Np / 64, 5), 64, 0, stream>>>(x, Wq, bq, Wk, bk, Wv, bv,
                                                       Qp, Kp, Vb);
    zsum_v3<<<dim3(Np / 64, NSL, Bn), 256, 0, stream>>>(Qp, Kp, ZP);
    zred<<<Bn * Np / 256, 256, 0, stream>>>(ZP, Lg);
    attn_v4<<<dim3(Np / 128, SL, Bn), 256, 0, stream>>>(Qp, Kp, Vb, Lg,
                                                        PO, Np / SL, SL);
    combine_kernel<<<Bn * Cc * Np / (256 * 8), 256, 0, stream>>>(PO, x, gamma, out, SL);
}

// Round 13
// 121.388 us; speedup vs baseline: 1.2387x; 1.1645x over previous
//
#include <hip/hip_runtime.h>

// SelfAttention (SAGAN-style), MI355X — bf16 MFMA implementation, v13.
// Math: out[b,c,n] = gamma * sum_m [exp(S[m,n]) / Z[m]] * V[b,c,m] + x[b,c,n]
//   S[m,n] = sum_q Q[q,m] K[q,n],  Z[m] = sum_j exp(S[m,j]).
// exp2 trick: Q pre-scaled by log2(e); L[m] = -log2(Z[m]) folded into the
// S-MFMA accumulator init => P = exp2(S' + L) with zero extra VALU.
//
// v13 (R12 post-mortem): v12 passed at 141.4; attn still 48.2 and ~90%
// stalled (issue-bound estimate ~4 µs). Binding constraint: each of the 4
// waves redundantly global-loads the same 4 KB V tile at point of use
// (FETCH 13 MB ~ 3x unique). Fix: cooperative LDS double-buffered V staging
// with a one-iteration register prefetch of the staging quantum (+4 VGPR
// only — R10 showed fat per-wave prefetch regresses). One barrier/iter;
// Plds logic untouched. ONLY attn changes vs v12.
// Failure clusters (do not reintroduce): 512-thread attn (v6/v7);
// dense [n][8] Q/K + quad-predicated frag loads (v11).

constexpr int Bn = 4, Cc = 64, Q8 = 8, Np = 4096;
constexpr int QK_STR = 32;  // padded q dim (shorts) per position
constexpr int PSTR = 40;    // attn Plds row stride in shorts (80B, 16B-aligned)
constexpr int VSTR = 32;    // attn Vlds row stride in shorts (64B; lane*16B linear, conflict-free)
constexpr int NSL = 8;      // zsum n-slices
constexpr int XSTR = 72;    // qkv xT row stride in shorts (144B, 16B-aligned)

typedef float f32x4 __attribute__((ext_vector_type(4)));
typedef short short8 __attribute__((ext_vector_type(8)));

__device__ inline unsigned int f2bf(float x) {  // RNE f32->bf16 (as u16)
    unsigned int u = __float_as_uint(x);
    u += 0x7fff + ((u >> 16) & 1);
    return u >> 16;
}
__device__ inline float bf2f(unsigned int u) { return __uint_as_float(u << 16); }

__device__ inline unsigned cvt_pk_bf16(float a, float b) {  // lo=bf16(a), hi=bf16(b)
    unsigned r;
    asm("v_cvt_pk_bf16_f32 %0, %1, %2" : "=v"(r) : "v"(a), "v"(b));
    return r;
}
__device__ inline float exp2g(float x) {
#if __has_builtin(__builtin_amdgcn_exp2f)
    return __builtin_amdgcn_exp2f(x);
#else
    return exp2f(x);
#endif
}
__device__ inline float log2g(float x) {
#if __has_builtin(__builtin_amdgcn_logf)
    return __builtin_amdgcn_logf(x);
#else
    return log2f(x);
#endif
}

// ---------------- kernel 1: QKV projections via MFMA (padded Q/K output) ----------------
__global__ __launch_bounds__(64) void qkv_mfma(
    const float* __restrict__ x,
    const float* __restrict__ Wq, const float* __restrict__ bq,
    const float* __restrict__ Wk, const float* __restrict__ bk,
    const float* __restrict__ Wv, const float* __restrict__ bv,
    unsigned short* __restrict__ Qp, unsigned short* __restrict__ Kp,
    unsigned short* __restrict__ Vb)
{
    __shared__ unsigned short xT[64 * XSTR];  // [n_local][c] bf16
    const int lane = threadIdx.x;
    const int quad = lane >> 4, l15 = lane & 15;
    const int gpos = blockIdx.x * 64;        // over Bn*Np
    const int ot = blockIdx.y;               // 0..4
    const int b = gpos >> 12, n0 = gpos & (Np - 1);
    const float LOG2E = 1.4426950408889634f;

    {
        const float* xrow = x + (size_t)(b * Cc + lane) * Np + n0;
        #pragma unroll
        for (int i4 = 0; i4 < 16; i4++) {
            float4 v = *(const float4*)&xrow[i4 * 4];
            int nb4 = i4 * 4;
            xT[(nb4 + 0) * XSTR + lane] = (unsigned short)f2bf(v.x);
            xT[(nb4 + 1) * XSTR + lane] = (unsigned short)f2bf(v.y);
            xT[(nb4 + 2) * XSTR + lane] = (unsigned short)f2bf(v.z);
            xT[(nb4 + 3) * XSTR + lane] = (unsigned short)f2bf(v.w);
        }
    }
    __syncthreads();

    const float* Wrow;
    if (ot == 0) Wrow = (l15 < 8) ? (Wq + l15 * Cc) : (Wk + (l15 - 8) * Cc);
    else         Wrow = Wv + ((ot - 1) * 16 + l15) * Cc;
    short8 wa[2];
    #pragma unroll
    for (int kf = 0; kf < 2; kf++) {
        #pragma unroll
        for (int jj = 0; jj < 8; jj++)
            wa[kf][jj] = (short)f2bf(Wrow[kf * 32 + quad * 8 + jj]);
    }
    float bias[4];
    if (ot == 0) {
        const float* bb = (quad < 2) ? bq : bk;
        int off = (quad & 1) * 4;
        #pragma unroll
        for (int r = 0; r < 4; r++) bias[r] = bb[off + r];
    } else {
        #pragma unroll
        for (int r = 0; r < 4; r++) bias[r] = bv[(ot - 1) * 16 + quad * 4 + r];
    }

    #pragma unroll
    for (int nt = 0; nt < 4; nt++) {
        short8 xb0 = *(const short8*)&xT[(nt * 16 + l15) * XSTR + quad * 8];
        short8 xb1 = *(const short8*)&xT[(nt * 16 + l15) * XSTR + 32 + quad * 8];
        f32x4 cc = __builtin_amdgcn_mfma_f32_16x16x32_bf16(
            wa[0], xb0, f32x4{0.f, 0.f, 0.f, 0.f}, 0, 0, 0);
        cc = __builtin_amdgcn_mfma_f32_16x16x32_bf16(wa[1], xb1, cc, 0, 0, 0);
        int n = n0 + nt * 16 + l15;
        if (ot == 0) {
            float v0 = cc[0] + bias[0], v1 = cc[1] + bias[1];
            float v2 = cc[2] + bias[2], v3 = cc[3] + bias[3];
            if (quad < 2) { v0 *= LOG2E; v1 *= LOG2E; v2 *= LOG2E; v3 *= LOG2E; }
            unsigned p01 = cvt_pk_bf16(v0, v1), p23 = cvt_pk_bf16(v2, v3);
            unsigned short* rowp = (quad < 2 ? Qp : Kp)
                + ((size_t)(b * Np + n)) * QK_STR;
            *(uint2*)(rowp + (quad & 1) * 4) = make_uint2(p01, p23);
            if ((quad & 1) == 0) {
                *(uint4*)(rowp + 8) = make_uint4(0, 0, 0, 0);
            } else {
                *(uint4*)(rowp + 16) = make_uint4(0, 0, 0, 0);
                *(uint4*)(rowp + 24) = make_uint4(0, 0, 0, 0);
            }
        } else {
            #pragma unroll
            for (int r = 0; r < 4; r++) {
                int vr = (ot - 1) * 16 + quad * 4 + r;
                Vb[(size_t)(b * Cc + vr) * Np + n] =
                    (unsigned short)f2bf(cc[r] + bias[r]);
            }
        }
    }
}

// ---------------- kernel 2: Z partials via MFMA, direct-from-L2 ----------------
__global__ __launch_bounds__(256) void zsum_v3(
    const unsigned short* __restrict__ Qp, const unsigned short* __restrict__ Kp,
    float* __restrict__ ZP)
{
    const int tid = threadIdx.x, w = tid >> 6, lane = tid & 63;
    const int quad = lane >> 4, l15 = lane & 15;
    const int bz = blockIdx.z, ns = blockIdx.y;
    const int m0 = blockIdx.x * 64 + w * 16;

    short8 qa = *(const short8*)&Qp[((size_t)(bz * Np + m0 + l15)) * QK_STR + quad * 8];
    const unsigned short* kbase = Kp + (size_t)bz * Np * QK_STR;
    const int nbase = ns * (Np / NSL);

    float z0 = 0.f, z1 = 0.f, z2 = 0.f, z3 = 0.f;
    #pragma unroll 4
    for (int nt = 0; nt < Np / NSL; nt += 16) {
        short8 kb = *(const short8*)
            &kbase[(size_t)(nbase + nt + l15) * QK_STR + quad * 8];
        f32x4 s = __builtin_amdgcn_mfma_f32_16x16x32_bf16(
            qa, kb, f32x4{0.f, 0.f, 0.f, 0.f}, 0, 0, 0);
        z0 += exp2g(s[0]); z1 += exp2g(s[1]);
        z2 += exp2g(s[2]); z3 += exp2g(s[3]);
    }
    #pragma unroll
    for (int mask = 1; mask < 16; mask <<= 1) {
        z0 += __shfl_xor(z0, mask); z1 += __shfl_xor(z1, mask);
        z2 += __shfl_xor(z2, mask); z3 += __shfl_xor(z3, mask);
    }
    if (l15 == 0) {
        float4 v = make_float4(z0, z1, z2, z3);
        *(float4*)&ZP[((size_t)(bz * NSL + ns)) * Np + m0 + quad * 4] = v;
    }
}

// ---------------- kernel 3: L[m] = -log2(Z[m]) ----------------
__global__ __launch_bounds__(256) void zred(
    const float* __restrict__ ZP, float* __restrict__ Lg)
{
    int i = blockIdx.x * 256 + threadIdx.x;  // over Bn*Np
    int b = i >> 12, m = i & (Np - 1);
    float z = 0.f;
    #pragma unroll
    for (int s = 0; s < NSL; s++) z += ZP[((size_t)(b * NSL + s)) * Np + m];
    Lg[(size_t)b * Np + m] = -log2g(z);
}

// ---------------- kernel 4: out partials via MFMA, LDS-staged V ----------------
// Geometry as proven v4: grid (Np/128, SL, Bn), block 256 (4 waves), wave w
// owns 32 n; Plds rows wave-private. NEW: V tile cooperatively staged into a
// double-buffered LDS region (lane*16B linear layout), register-prefetched
// one iteration ahead. One barrier per iter fences buffer reuse.
__global__ __launch_bounds__(256) void attn_v8(
    const unsigned short* __restrict__ Qp, const unsigned short* __restrict__ Kp,
    const unsigned short* __restrict__ Vb, const float* __restrict__ Lg,
    unsigned short* __restrict__ PO, int Ms, int SL)
{
    __shared__ unsigned short Plds[128 * PSTR];     // [n_local][m_local]
    __shared__ unsigned short Vlds[2][64 * VSTR];   // [c][m_local 0..31]
    const int tid = threadIdx.x, w = tid >> 6, lane = tid & 63;
    const int quad = lane >> 4, l15 = lane & 15;
    const int bz = blockIdx.z, by = blockIdx.y, nb = blockIdx.x * 128;

    // staging role: thread t covers V row c = t>>2, m-chunk = t&3 (8 shorts)
    const int sc = tid >> 2, sch = tid & 3;
    const unsigned short* vsrc = Vb + (size_t)(bz * Cc + sc) * Np + sch * 8;

    short8 kf[2];
    #pragma unroll
    for (int t = 0; t < 2; t++) {
        int n = nb + (2 * w + t) * 16 + l15;
        kf[t] = *(const short8*)&Kp[((size_t)(bz * Np + n)) * QK_STR + quad * 8];
    }
    f32x4 acc[4][2];
    #pragma unroll
    for (int ct = 0; ct < 4; ct++)
        #pragma unroll
        for (int t = 0; t < 2; t++) acc[ct][t] = f32x4{0.f, 0.f, 0.f, 0.f};

    const int m_base = by * Ms;

    // prologue: tile 0 -> buf 0
    {
        uint4 p0 = *(const uint4*)&vsrc[m_base];
        *(uint4*)&Vlds[0][sc * VSTR + sch * 8] = p0;
    }

    for (int mi = 0; mi < Ms; mi += 32) {
        const int m0 = m_base + mi;
        const int cur = (mi >> 5) & 1;
        // prefetch next V tile into registers (wrap: harmless on last iter)
        const int mn = m_base + ((mi + 32) & (Ms - 1));
        uint4 pfN = *(const uint4*)&vsrc[mn];

        __syncthreads();  // publishes buf[cur]; fences reuse of buf[cur^1]

        // phase 1: P[m0..m0+31][wave's 32 n] = exp2(S' + L[m]), bf16, into LDS
        #pragma unroll
        for (int mt = 0; mt < 2; mt++) {
            short8 qa = *(const short8*)
                &Qp[((size_t)(bz * Np + m0 + mt * 16 + l15)) * QK_STR + quad * 8];
            f32x4 Lc = *(const f32x4*)
                &Lg[(size_t)bz * Np + m0 + mt * 16 + quad * 4];
            #pragma unroll
            for (int t = 0; t < 2; t++) {
                f32x4 s = __builtin_amdgcn_mfma_f32_16x16x32_bf16(qa, kf[t], Lc, 0, 0, 0);
                unsigned p01 = cvt_pk_bf16(exp2g(s[0]), exp2g(s[1]));
                unsigned p23 = cvt_pk_bf16(exp2g(s[2]), exp2g(s[3]));
                int nl = (2 * w + t) * 16 + l15;
                *(uint2*)&Plds[nl * PSTR + mt * 16 + quad * 4] = make_uint2(p01, p23);
            }
        }
        // phase 2: acc[c, n] += V[c, m0..31] * P[m0..31, n]
        short8 pb[2];
        #pragma unroll
        for (int t = 0; t < 2; t++)
            pb[t] = *(const short8*)&Plds[(w * 32 + t * 16 + l15) * PSTR + quad * 8];
        #pragma unroll
        for (int ct = 0; ct < 4; ct++) {
            short8 ua = *(const short8*)&Vlds[cur][(ct * 16 + l15) * VSTR + quad * 8];
            #pragma unroll
            for (int t = 0; t < 2; t++)
                acc[ct][t] = __builtin_amdgcn_mfma_f32_16x16x32_bf16(
                    ua, pb[t], acc[ct][t], 0, 0, 0);
        }
        // publish next tile into the other buffer (fenced by next barrier)
        *(uint4*)&Vlds[cur ^ 1][sc * VSTR + sch * 8] = pfN;
    }
    unsigned short* po = PO + ((size_t)((bz * SL + by) * Cc)) * Np + nb;
    #pragma unroll
    for (int ct = 0; ct < 4; ct++)
        #pragma unroll
        for (int t = 0; t < 2; t++) {
            int c = ct * 16 + quad * 4, n = w * 32 + t * 16 + l15;
            #pragma unroll
            for (int r = 0; r < 4; r++)
                po[(size_t)(c + r) * Np + n] = (unsigned short)f2bf(acc[ct][t][r]);
        }
}

// ---------------- kernel 5: combine slices + gamma*out + x (8-wide) ----------------
__global__ __launch_bounds__(256) void combine_kernel(
    const unsigned short* __restrict__ PO, const float* __restrict__ x,
    const float* __restrict__ gamma, float* __restrict__ out, int sl2)
{
    int idx8 = (blockIdx.x * 256 + threadIdx.x) * 8;  // over Bn*Cc*Np
    int b = idx8 >> 18;
    int c = (idx8 >> 12) & 63;
    int n = idx8 & (Np - 1);
    float o[8];
    #pragma unroll
    for (int i = 0; i < 8; i++) o[i] = 0.f;
    for (int sl = 0; sl < sl2; ++sl) {
        uint4 u = *(const uint4*)&PO[(size_t)((b * sl2 + sl) * Cc + c) * Np + n];
        o[0] += bf2f(u.x & 0xffff); o[1] += bf2f(u.x >> 16);
        o[2] += bf2f(u.y & 0xffff); o[3] += bf2f(u.y >> 16);
        o[4] += bf2f(u.z & 0xffff); o[5] += bf2f(u.z >> 16);
        o[6] += bf2f(u.w & 0xffff); o[7] += bf2f(u.w >> 16);
    }
    float g = gamma[0];
    float4 x0 = *(const float4*)&x[idx8];
    float4 x1 = *(const float4*)&x[idx8 + 4];
    float4 r0 = make_float4(g * o[0] + x0.x, g * o[1] + x0.y,
                            g * o[2] + x0.z, g * o[3] + x0.w);
    float4 r1 = make_float4(g * o[4] + x1.x, g * o[5] + x1.y,
                            g * o[6] + x1.z, g * o[7] + x1.w);
    *(float4*)&out[idx8] = r0;
    *(float4*)&out[idx8 + 4] = r1;
}

extern "C" void kernel_launch(void* const* d_in, const int* in_sizes, int n_in,
                              void* d_out, int out_size, void* d_ws, size_t ws_size,
                              hipStream_t stream)
{
    const float* x     = (const float*)d_in[0];
    const float* Wq    = (const float*)d_in[1];
    const float* bq    = (const float*)d_in[2];
    const float* Wk    = (const float*)d_in[3];
    const float* bk    = (const float*)d_in[4];
    const float* Wv    = (const float*)d_in[5];
    const float* bv    = (const float*)d_in[6];
    const float* gamma = (const float*)d_in[7];
    float* out = (float*)d_out;

    unsigned short* Qp = (unsigned short*)d_ws;               // 1 MB (padded [n][32])
    unsigned short* Kp = Qp + (size_t)Bn * Np * QK_STR;       // 1 MB
    unsigned short* Vb = Kp + (size_t)Bn * Np * QK_STR;       // 2 MB (bf16 V)
    float* Lg   = (float*)(Vb + (size_t)Bn * Cc * Np);        // 64 KB: -log2(Z)
    float* ZP   = Lg + (size_t)Bn * Np;                       // NSL partials, 512 KB
    unsigned short* PO = (unsigned short*)(ZP + (size_t)Bn * NSL * Np);  // SL * 2 MB

    size_t baseB = (size_t)Bn * Np * QK_STR * 2 * 2 + (size_t)Bn * Cc * Np * 2
                 + (size_t)Bn * Np * 4 + (size_t)Bn * NSL * Np * 4;
    int SL = 8;  // m-slices for attn partials (1024 blocks)
    while (SL > 1 && baseB + (size_t)Bn * SL * Cc * Np * 2 > ws_size) SL >>= 1;

    qkv_mfma<<<dim3(Bn * Np / 64, 5), 64, 0, stream>>>(x, Wq, bq, Wk, bk, Wv, bv,
                                                       Qp, Kp, Vb);
    zsum_v3<<<dim3(Np / 64, NSL, Bn), 256, 0, stream>>>(Qp, Kp, ZP);
    zred<<<Bn * Np / 256, 256, 0, stream>>>(ZP, Lg);
    attn_v8<<<dim3(Np / 128, SL, Bn), 256, 0, stream>>>(Qp, Kp, Vb, Lg,
                                                        PO, Np / SL, SL);
    combine_kernel<<<Bn * Cc * Np / (256 * 8), 256, 0, stream>>>(PO, x, gamma, out, SL);
}

// Round 15
// 119.791 us; speedup vs baseline: 1.2552x; 1.0133x over previous
//
#include <hip/hip_runtime.h>

// SelfAttention (SAGAN-style), MI355X — bf16 MFMA implementation, v15.
// Math: out[b,c,n] = gamma * sum_m [exp(S[m,n]) / Z[m]] * V[b,c,m] + x[b,c,n]
//   S[m,n] = sum_q Q[q,m] K[q,n],  Z[m] = sum_j exp(S[m,j]).
// exp2 trick: Q pre-scaled by log2(e); L[m] = -log2(Z[m]) folded into the
// S-MFMA accumulator init => P = exp2(S' + L) with zero extra VALU.
//
// v15 (R14 post-mortem): v14 changed zsum AND attn simultaneously and
// failed unattributably (absmax ~1224, unnormalized-scale family). v15 =
// v13 verbatim (121.4 µs proven) + ONLY zsum_v6 (2 m-tiles/wave, no LDS,
// no barriers). attn_v9's Q/L LDS staging is condemned pending attribution.
// Failure clusters (do not reintroduce): 512-thread attn (v6/v7);
// dense [n][8] Q/K + quad-predicated frag loads (v11); fat per-wave
// register prefetch in attn (v10); v14's combined zsum_v6+attn_v9 (this
// round isolates zsum_v6).

constexpr int Bn = 4, Cc = 64, Q8 = 8, Np = 4096;
constexpr int QK_STR = 32;  // padded q dim (shorts) per position
constexpr int PSTR = 40;    // attn Plds row stride in shorts (80B, 16B-aligned)
constexpr int VSTR = 32;    // attn Vlds row stride in shorts (64B; lane*16B linear)
constexpr int NSL = 8;      // zsum n-slices
constexpr int XSTR = 72;    // qkv xT row stride in shorts (144B, 16B-aligned)

typedef float f32x4 __attribute__((ext_vector_type(4)));
typedef short short8 __attribute__((ext_vector_type(8)));

__device__ inline unsigned int f2bf(float x) {  // RNE f32->bf16 (as u16)
    unsigned int u = __float_as_uint(x);
    u += 0x7fff + ((u >> 16) & 1);
    return u >> 16;
}
__device__ inline float bf2f(unsigned int u) { return __uint_as_float(u << 16); }

__device__ inline unsigned cvt_pk_bf16(float a, float b) {  // lo=bf16(a), hi=bf16(b)
    unsigned r;
    asm("v_cvt_pk_bf16_f32 %0, %1, %2" : "=v"(r) : "v"(a), "v"(b));
    return r;
}
__device__ inline float exp2g(float x) {
#if __has_builtin(__builtin_amdgcn_exp2f)
    return __builtin_amdgcn_exp2f(x);
#else
    return exp2f(x);
#endif
}
__device__ inline float log2g(float x) {
#if __has_builtin(__builtin_amdgcn_logf)
    return __builtin_amdgcn_logf(x);
#else
    return log2f(x);
#endif
}

// ---------------- kernel 1: QKV projections via MFMA (padded Q/K output) ----------------
__global__ __launch_bounds__(64) void qkv_mfma(
    const float* __restrict__ x,
    const float* __restrict__ Wq, const float* __restrict__ bq,
    const float* __restrict__ Wk, const float* __restrict__ bk,
    const float* __restrict__ Wv, const float* __restrict__ bv,
    unsigned short* __restrict__ Qp, unsigned short* __restrict__ Kp,
    unsigned short* __restrict__ Vb)
{
    __shared__ unsigned short xT[64 * XSTR];  // [n_local][c] bf16
    const int lane = threadIdx.x;
    const int quad = lane >> 4, l15 = lane & 15;
    const int gpos = blockIdx.x * 64;        // over Bn*Np
    const int ot = blockIdx.y;               // 0..4
    const int b = gpos >> 12, n0 = gpos & (Np - 1);
    const float LOG2E = 1.4426950408889634f;

    {
        const float* xrow = x + (size_t)(b * Cc + lane) * Np + n0;
        #pragma unroll
        for (int i4 = 0; i4 < 16; i4++) {
            float4 v = *(const float4*)&xrow[i4 * 4];
            int nb4 = i4 * 4;
            xT[(nb4 + 0) * XSTR + lane] = (unsigned short)f2bf(v.x);
            xT[(nb4 + 1) * XSTR + lane] = (unsigned short)f2bf(v.y);
            xT[(nb4 + 2) * XSTR + lane] = (unsigned short)f2bf(v.z);
            xT[(nb4 + 3) * XSTR + lane] = (unsigned short)f2bf(v.w);
        }
    }
    __syncthreads();

    const float* Wrow;
    if (ot == 0) Wrow = (l15 < 8) ? (Wq + l15 * Cc) : (Wk + (l15 - 8) * Cc);
    else         Wrow = Wv + ((ot - 1) * 16 + l15) * Cc;
    short8 wa[2];
    #pragma unroll
    for (int kf = 0; kf < 2; kf++) {
        #pragma unroll
        for (int jj = 0; jj < 8; jj++)
            wa[kf][jj] = (short)f2bf(Wrow[kf * 32 + quad * 8 + jj]);
    }
    float bias[4];
    if (ot == 0) {
        const float* bb = (quad < 2) ? bq : bk;
        int off = (quad & 1) * 4;
        #pragma unroll
        for (int r = 0; r < 4; r++) bias[r] = bb[off + r];
    } else {
        #pragma unroll
        for (int r = 0; r < 4; r++) bias[r] = bv[(ot - 1) * 16 + quad * 4 + r];
    }

    #pragma unroll
    for (int nt = 0; nt < 4; nt++) {
        short8 xb0 = *(const short8*)&xT[(nt * 16 + l15) * XSTR + quad * 8];
        short8 xb1 = *(const short8*)&xT[(nt * 16 + l15) * XSTR + 32 + quad * 8];
        f32x4 cc = __builtin_amdgcn_mfma_f32_16x16x32_bf16(
            wa[0], xb0, f32x4{0.f, 0.f, 0.f, 0.f}, 0, 0, 0);
        cc = __builtin_amdgcn_mfma_f32_16x16x32_bf16(wa[1], xb1, cc, 0, 0, 0);
        int n = n0 + nt * 16 + l15;
        if (ot == 0) {
            float v0 = cc[0] + bias[0], v1 = cc[1] + bias[1];
            float v2 = cc[2] + bias[2], v3 = cc[3] + bias[3];
            if (quad < 2) { v0 *= LOG2E; v1 *= LOG2E; v2 *= LOG2E; v3 *= LOG2E; }
            unsigned p01 = cvt_pk_bf16(v0, v1), p23 = cvt_pk_bf16(v2, v3);
            unsigned short* rowp = (quad < 2 ? Qp : Kp)
                + ((size_t)(b * Np + n)) * QK_STR;
            *(uint2*)(rowp + (quad & 1) * 4) = make_uint2(p01, p23);
            if ((quad & 1) == 0) {
                *(uint4*)(rowp + 8) = make_uint4(0, 0, 0, 0);
            } else {
                *(uint4*)(rowp + 16) = make_uint4(0, 0, 0, 0);
                *(uint4*)(rowp + 24) = make_uint4(0, 0, 0, 0);
            }
        } else {
            #pragma unroll
            for (int r = 0; r < 4; r++) {
                int vr = (ot - 1) * 16 + quad * 4 + r;
                Vb[(size_t)(b * Cc + vr) * Np + n] =
                    (unsigned short)f2bf(cc[r] + bias[r]);
            }
        }
    }
}

// ---------------- kernel 2: Z partials via MFMA, 2 m-tiles/wave ----------------
// grid (Np/128, NSL, Bn), block 256 (4 waves). Wave w: m in [m0, m0+32),
// m0 = bx*128 + w*32. Per K B-frag load: 2 MFMAs + 8 exp2. No LDS/barriers.
__global__ __launch_bounds__(256) void zsum_v6(
    const unsigned short* __restrict__ Qp, const unsigned short* __restrict__ Kp,
    float* __restrict__ ZP)
{
    const int tid = threadIdx.x, w = tid >> 6, lane = tid & 63;
    const int quad = lane >> 4, l15 = lane & 15;
    const int bz = blockIdx.z, ns = blockIdx.y;
    const int m0 = blockIdx.x * 128 + w * 32;

    short8 qa0 = *(const short8*)
        &Qp[((size_t)(bz * Np + m0 + l15)) * QK_STR + quad * 8];
    short8 qa1 = *(const short8*)
        &Qp[((size_t)(bz * Np + m0 + 16 + l15)) * QK_STR + quad * 8];
    const unsigned short* kbase = Kp + (size_t)bz * Np * QK_STR;
    const int nbase = ns * (Np / NSL);

    float z0 = 0.f, z1 = 0.f, z2 = 0.f, z3 = 0.f;
    float z4 = 0.f, z5 = 0.f, z6 = 0.f, z7 = 0.f;
    #pragma unroll 4
    for (int nt = 0; nt < Np / NSL; nt += 16) {
        short8 kb = *(const short8*)
            &kbase[(size_t)(nbase + nt + l15) * QK_STR + quad * 8];
        f32x4 s0 = __builtin_amdgcn_mfma_f32_16x16x32_bf16(
            qa0, kb, f32x4{0.f, 0.f, 0.f, 0.f}, 0, 0, 0);
        f32x4 s1 = __builtin_amdgcn_mfma_f32_16x16x32_bf16(
            qa1, kb, f32x4{0.f, 0.f, 0.f, 0.f}, 0, 0, 0);
        z0 += exp2g(s0[0]); z1 += exp2g(s0[1]);
        z2 += exp2g(s0[2]); z3 += exp2g(s0[3]);
        z4 += exp2g(s1[0]); z5 += exp2g(s1[1]);
        z6 += exp2g(s1[2]); z7 += exp2g(s1[3]);
    }
    #pragma unroll
    for (int mask = 1; mask < 16; mask <<= 1) {
        z0 += __shfl_xor(z0, mask); z1 += __shfl_xor(z1, mask);
        z2 += __shfl_xor(z2, mask); z3 += __shfl_xor(z3, mask);
        z4 += __shfl_xor(z4, mask); z5 += __shfl_xor(z5, mask);
        z6 += __shfl_xor(z6, mask); z7 += __shfl_xor(z7, mask);
    }
    if (l15 == 0) {
        float* zp = &ZP[((size_t)(bz * NSL + ns)) * Np + m0];
        *(float4*)&zp[quad * 4] = make_float4(z0, z1, z2, z3);
        *(float4*)&zp[16 + quad * 4] = make_float4(z4, z5, z6, z7);
    }
}

// ---------------- kernel 3: L[m] = -log2(Z[m]) ----------------
__global__ __launch_bounds__(256) void zred(
    const float* __restrict__ ZP, float* __restrict__ Lg)
{
    int i = blockIdx.x * 256 + threadIdx.x;  // over Bn*Np
    int b = i >> 12, m = i & (Np - 1);
    float z = 0.f;
    #pragma unroll
    for (int s = 0; s < NSL; s++) z += ZP[((size_t)(b * NSL + s)) * Np + m];
    Lg[(size_t)b * Np + m] = -log2g(z);
}

// ---------------- kernel 4: out partials via MFMA, LDS-staged V (v13 verbatim) ----------------
__global__ __launch_bounds__(256) void attn_v8(
    const unsigned short* __restrict__ Qp, const unsigned short* __restrict__ Kp,
    const unsigned short* __restrict__ Vb, const float* __restrict__ Lg,
    unsigned short* __restrict__ PO, int Ms, int SL)
{
    __shared__ unsigned short Plds[128 * PSTR];     // [n_local][m_local]
    __shared__ unsigned short Vlds[2][64 * VSTR];   // [c][m_local 0..31]
    const int tid = threadIdx.x, w = tid >> 6, lane = tid & 63;
    const int quad = lane >> 4, l15 = lane & 15;
    const int bz = blockIdx.z, by = blockIdx.y, nb = blockIdx.x * 128;

    // staging role: thread t covers V row c = t>>2, m-chunk = t&3 (8 shorts)
    const int sc = tid >> 2, sch = tid & 3;
    const unsigned short* vsrc = Vb + (size_t)(bz * Cc + sc) * Np + sch * 8;

    short8 kf[2];
    #pragma unroll
    for (int t = 0; t < 2; t++) {
        int n = nb + (2 * w + t) * 16 + l15;
        kf[t] = *(const short8*)&Kp[((size_t)(bz * Np + n)) * QK_STR + quad * 8];
    }
    f32x4 acc[4][2];
    #pragma unroll
    for (int ct = 0; ct < 4; ct++)
        #pragma unroll
        for (int t = 0; t < 2; t++) acc[ct][t] = f32x4{0.f, 0.f, 0.f, 0.f};

    const int m_base = by * Ms;

    // prologue: tile 0 -> buf 0
    {
        uint4 p0 = *(const uint4*)&vsrc[m_base];
        *(uint4*)&Vlds[0][sc * VSTR + sch * 8] = p0;
    }

    for (int mi = 0; mi < Ms; mi += 32) {
        const int m0 = m_base + mi;
        const int cur = (mi >> 5) & 1;
        // prefetch next V tile into registers (wrap: harmless on last iter)
        const int mn = m_base + ((mi + 32) & (Ms - 1));
        uint4 pfN = *(const uint4*)&vsrc[mn];

        __syncthreads();  // publishes buf[cur]; fences reuse of buf[cur^1]

        // phase 1: P[m0..m0+31][wave's 32 n] = exp2(S' + L[m]), bf16, into LDS
        #pragma unroll
        for (int mt = 0; mt < 2; mt++) {
            short8 qa = *(const short8*)
                &Qp[((size_t)(bz * Np + m0 + mt * 16 + l15)) * QK_STR + quad * 8];
            f32x4 Lc = *(const f32x4*)
                &Lg[(size_t)bz * Np + m0 + mt * 16 + quad * 4];
            #pragma unroll
            for (int t = 0; t < 2; t++) {
                f32x4 s = __builtin_amdgcn_mfma_f32_16x16x32_bf16(qa, kf[t], Lc, 0, 0, 0);
                unsigned p01 = cvt_pk_bf16(exp2g(s[0]), exp2g(s[1]));
                unsigned p23 = cvt_pk_bf16(exp2g(s[2]), exp2g(s[3]));
                int nl = (2 * w + t) * 16 + l15;
                *(uint2*)&Plds[nl * PSTR + mt * 16 + quad * 4] = make_uint2(p01, p23);
            }
        }
        // phase 2: acc[c, n] += V[c, m0..31] * P[m0..31, n]
        short8 pb[2];
        #pragma unroll
        for (int t = 0; t < 2; t++)
            pb[t] = *(const short8*)&Plds[(w * 32 + t * 16 + l15) * PSTR + quad * 8];
        #pragma unroll
        for (int ct = 0; ct < 4; ct++) {
            short8 ua = *(const short8*)&Vlds[cur][(ct * 16 + l15) * VSTR + quad * 8];
            #pragma unroll
            for (int t = 0; t < 2; t++)
                acc[ct][t] = __builtin_amdgcn_mfma_f32_16x16x32_bf16(
                    ua, pb[t], acc[ct][t], 0, 0, 0);
        }
        // publish next tile into the other buffer (fenced by next barrier)
        *(uint4*)&Vlds[cur ^ 1][sc * VSTR + sch * 8] = pfN;
    }
    unsigned short* po = PO + ((size_t)((bz * SL + by) * Cc)) * Np + nb;
    #pragma unroll
    for (int ct = 0; ct < 4; ct++)
        #pragma unroll
        for (int t = 0; t < 2; t++) {
            int c = ct * 16 + quad * 4, n = w * 32 + t * 16 + l15;
            #pragma unroll
            for (int r = 0; r < 4; r++)
                po[(size_t)(c + r) * Np + n] = (unsigned short)f2bf(acc[ct][t][r]);
        }
}

// ---------------- kernel 5: combine slices + gamma*out + x (8-wide) ----------------
__global__ __launch_bounds__(256) void combine_kernel(
    const unsigned short* __restrict__ PO, const float* __restrict__ x,
    const float* __restrict__ gamma, float* __restrict__ out, int sl2)
{
    int idx8 = (blockIdx.x * 256 + threadIdx.x) * 8;  // over Bn*Cc*Np
    int b = idx8 >> 18;
    int c = (idx8 >> 12) & 63;
    int n = idx8 & (Np - 1);
    float o[8];
    #pragma unroll
    for (int i = 0; i < 8; i++) o[i] = 0.f;
    for (int sl = 0; sl < sl2; ++sl) {
        uint4 u = *(const uint4*)&PO[(size_t)((b * sl2 + sl) * Cc + c) * Np + n];
        o[0] += bf2f(u.x & 0xffff); o[1] += bf2f(u.x >> 16);
        o[2] += bf2f(u.y & 0xffff); o[3] += bf2f(u.y >> 16);
        o[4] += bf2f(u.z & 0xffff); o[5] += bf2f(u.z >> 16);
        o[6] += bf2f(u.w & 0xffff); o[7] += bf2f(u.w >> 16);
    }
    float g = gamma[0];
    float4 x0 = *(const float4*)&x[idx8];
    float4 x1 = *(const float4*)&x[idx8 + 4];
    float4 r0 = make_float4(g * o[0] + x0.x, g * o[1] + x0.y,
                            g * o[2] + x0.z, g * o[3] + x0.w);
    float4 r1 = make_float4(g * o[4] + x1.x, g * o[5] + x1.y,
                            g * o[6] + x1.z, g * o[7] + x1.w);
    *(float4*)&out[idx8] = r0;
    *(float4*)&out[idx8 + 4] = r1;
}

extern "C" void kernel_launch(void* const* d_in, const int* in_sizes, int n_in,
                              void* d_out, int out_size, void* d_ws, size_t ws_size,
                              hipStream_t stream)
{
    const float* x     = (const float*)d_in[0];
    const float* Wq    = (const float*)d_in[1];
    const float* bq    = (const float*)d_in[2];
    const float* Wk    = (const float*)d_in[3];
    const float* bk    = (const float*)d_in[4];
    const float* Wv    = (const float*)d_in[5];
    const float* bv    = (const float*)d_in[6];
    const float* gamma = (const float*)d_in[7];
    float* out = (float*)d_out;

    unsigned short* Qp = (unsigned short*)d_ws;               // 1 MB (padded [n][32])
    unsigned short* Kp = Qp + (size_t)Bn * Np * QK_STR;       // 1 MB
    unsigned short* Vb = Kp + (size_t)Bn * Np * QK_STR;       // 2 MB (bf16 V)
    float* Lg   = (float*)(Vb + (size_t)Bn * Cc * Np);        // 64 KB: -log2(Z)
    float* ZP   = Lg + (size_t)Bn * Np;                       // NSL partials, 512 KB
    unsigned short* PO = (unsigned short*)(ZP + (size_t)Bn * NSL * Np);  // SL * 2 MB

    size_t baseB = (size_t)Bn * Np * QK_STR * 2 * 2 + (size_t)Bn * Cc * Np * 2
                 + (size_t)Bn * Np * 4 + (size_t)Bn * NSL * Np * 4;
    int SL = 8;  // m-slices for attn partials (1024 blocks)
    while (SL > 1 && baseB + (size_t)Bn * SL * Cc * Np * 2 > ws_size) SL >>= 1;

    qkv_mfma<<<dim3(Bn * Np / 64, 5), 64, 0, stream>>>(x, Wq, bq, Wk, bk, Wv, bv,
                                                       Qp, Kp, Vb);
    zsum_v6<<<dim3(Np / 128, NSL, Bn), 256, 0, stream>>>(Qp, Kp, ZP);
    zred<<<Bn * Np / 256, 256, 0, stream>>>(ZP, Lg);
    attn_v8<<<dim3(Np / 128, SL, Bn), 256, 0, stream>>>(Qp, Kp, Vb, Lg,
                                                        PO, Np / SL, SL);
    combine_kernel<<<Bn * Cc * Np / (256 * 8), 256, 0, stream>>>(PO, x, gamma, out, SL);
}